// Round 11
// baseline (660.760 us; speedup 1.0000x reference)
//
#include <hip/hip_runtime.h>
#include <hip/hip_cooperative_groups.h>

namespace cg = cooperative_groups;

#define NB     20000
#define NL     320000
#define NOTH   1000
#define BATCH  128
#define ROW    (2*NB + NOTH)   // 41000
#define CAP    80              // events/bus capacity; degree ~ Poisson(32), max ~60
#define NBLK   256             // grid: one block per CU (cooperative)
#define NTHR   1024
#define LSEG   (NL/NBLK)       // 1250 lines per block (histo/place)
#define HALF   (NB/2)          // 10000 buses per delta-half
#define SCANBK 20              // scan blocks (20*1024 >= 20000)
#define CPF4   (BATCH*(NB/4 + NOTH/4))   // voltages+other float4s: 672000
#define SMEMB  (NB*4 + NB*2)   // 120000 B: h/ang (80K) + pref (40K)

__device__ __forceinline__ float fast_rcp(float a)
{
    float r;
    asm volatile("v_rcp_f32 %0, %1" : "=v"(r) : "v"(a));
    return r;
}

// ---------------------------------------------------------------------------
// Single cooperative kernel: histo -> scan||copy -> place -> delta -> flows.
// Eliminates 4 kernel boundaries; angles2 stays in LDS between delta and
// flows (only the partner 40-KB half-row is re-read from global).
// ---------------------------------------------------------------------------
__global__ __launch_bounds__(NTHR, 1) void mega_k(
    const float* __restrict__ x, const int* __restrict__ fidx,
    const int* __restrict__ tidx, const float* __restrict__ xr,
    const float* __restrict__ lim, ushort* __restrict__ H,
    int* __restrict__ cnt, unsigned* __restrict__ bins,
    float* __restrict__ out, float* __restrict__ f2)
{
    extern __shared__ char sm[];
    uint*   __restrict__ h    = (uint*)sm;              // 80 KB (histo/place)
    float*  __restrict__ ang  = (float*)sm;             // 80 KB (delta/flows)
    ushort* __restrict__ pref = (ushort*)(sm + NB * 4); // 40 KB (place)

    const int blk = blockIdx.x;
    const int tid = threadIdx.x;
    cg::grid_group grid = cg::this_grid();
    const int l0 = blk * LSEG;

    // ---- PH: per-block histogram of its 1250-line segment -> u16 H row ----
    for (int i = tid; i < NB; i += NTHR) h[i] = 0u;
    __syncthreads();
    for (int l = l0 + tid; l < l0 + LSEG; l += NTHR) {
        atomicAdd(&h[fidx[l]], 1u);                    // LDS atomics
        atomicAdd(&h[tidx[l]], 1u);
    }
    __syncthreads();
    {
        ushort* __restrict__ Hrow = H + (size_t)blk * NB;
        for (int i = tid; i < NB / 2; i += NTHR) {
            ushort2 u; u.x = (ushort)h[2 * i]; u.y = (ushort)h[2 * i + 1];
            ((ushort2*)Hrow)[i] = u;
        }
    }
    __threadfence();
    grid.sync();

    // ---- PS: blocks 0..19 scan the 256 partials per bus (exclusive, in
    //      place) + emit cnt; blocks 20..255 copy voltages+other x->out ----
    if (blk < SCANBK) {
        const int u = blk * NTHR + tid;
        if (u < NB) {
            uint run = 0;
            for (int b = 0; b < NBLK; ++b) {
                const uint v = H[(size_t)b * NB + u];
                H[(size_t)b * NB + u] = (ushort)run;
                run += v;
            }
            cnt[u] = (int)run;
        }
    } else {
        const int nthr2 = (NBLK - SCANBK) * NTHR;
        for (int idx = (blk - SCANBK) * NTHR + tid; idx < CPF4; idx += nthr2) {
            const int b = idx / (NB / 4 + NOTH / 4);
            const int r = idx % (NB / 4 + NOTH / 4);
            const int off = (r < NB / 4) ? r : (2 * NB / 4) + (r - NB / 4);
            const size_t p = (size_t)b * (ROW / 4) + off;
            ((float4*)out)[p] = ((const float4*)x)[p];
        }
    }
    __threadfence();
    grid.sync();

    // ---- PP: place events. slot = staged global prefix + LDS local rank ---
    for (int i = tid; i < NB; i += NTHR) h[i] = 0u;
    {
        const uint* __restrict__ Hrow = (const uint*)(H + (size_t)blk * NB);
        for (int i = tid; i < NB / 2; i += NTHR) ((uint*)pref)[i] = Hrow[i];
    }
    __syncthreads();
    for (int l = l0 + tid; l < l0 + LSEG; l += NTHR) {
        const int fi = fidx[l];
        const int ti = tidx[l];
        union { float f; unsigned u; } c; c.f = xr[l] * lim[l];
        const unsigned rl16 = (c.u + 0x8000u) >> 16;
        const uint s0 = (uint)pref[fi] + atomicAdd(&h[fi], 1u);
        if (s0 < CAP) bins[(size_t)s0 * NB + fi] = ((unsigned)ti << 17) | rl16;
        const uint s1 = (uint)pref[ti] + atomicAdd(&h[ti], 1u);
        if (s1 < CAP) bins[(size_t)s1 * NB + ti] =
            ((unsigned)fi << 17) | (1u << 16) | rl16;
    }
    __threadfence();
    grid.sync();

    // ---- PD: delta. block (b, half) owns 10000 buses; angles row in LDS ---
    const int b    = blk & (BATCH - 1);                // XCD = b%8
    const int half = blk >> 7;
    const float* __restrict__ xrow = x   + (size_t)b * ROW;
    float*       __restrict__ orow = out + (size_t)b * ROW;

    for (int i = tid; i < NB / 4; i += NTHR)
        ((float4*)ang)[i] = ((const float4*)(xrow + NB))[i];
    __syncthreads();

    const int base = half * HALF;
    float a2v[10];
    #pragma unroll
    for (int k = 0; k < 10; ++k) {
        const int bus = base + k * NTHR + tid;
        a2v[k] = 0.0f;
        if (k * NTHR + tid < HALF) {
            const int   n  = min(cnt[bus], CAP);
            const float ab = ang[bus];
            float ds = 0.0f;
            int e = 0;
            #define CONTRIB(W)                                               \
            {                                                                \
                const unsigned w  = (W);                                     \
                const int   other = (int)(w >> 17);                          \
                const float rl    = __uint_as_float((w & 0xFFFFu) << 16);    \
                const float ad    = ab - ang[other];                         \
                if (fabsf(ad) > rl) {                                        \
                    float hh = 0.5f * (copysignf(rl, ad) - ad);              \
                    if (w & (1u << 16)) hh = -hh;                            \
                    ds += hh;                                                \
                }                                                            \
            }
            for (; e + 4 <= n; e += 4) {
                const unsigned w0 = bins[(size_t)(e + 0) * NB + bus];
                const unsigned w1 = bins[(size_t)(e + 1) * NB + bus];
                const unsigned w2 = bins[(size_t)(e + 2) * NB + bus];
                const unsigned w3 = bins[(size_t)(e + 3) * NB + bus];
                CONTRIB(w0) CONTRIB(w1) CONTRIB(w2) CONTRIB(w3)
            }
            for (; e < n; ++e) CONTRIB(bins[(size_t)e * NB + bus])
            #undef CONTRIB
            a2v[k] = ab + ds;
        }
    }
    __syncthreads();                                   // all gathers done
    #pragma unroll
    for (int k = 0; k < 10; ++k) {
        const int bus = base + k * NTHR + tid;
        if (k * NTHR + tid < HALF) {
            ang[bus]        = a2v[k];                  // LDS update for flows
            orow[NB + bus]  = a2v[k];                  // global angles2
        }
    }
    __threadfence();
    grid.sync();

    // ---- PF: flows. stage partner half-row from global; gather from LDS ---
    const int ohalf = half ^ 1;
    for (int i = tid; i < HALF / 4; i += NTHR)
        ((float4*)ang)[ohalf * (HALF / 4) + i] =
            ((const float4*)(orow + NB + ohalf * HALF))[i];
    __syncthreads();

    float* __restrict__ frow = f2 + (size_t)b * NL;
    const int q0 = half * (NL / 8);                    // f4-quads: 40000/half
    const int q1 = q0 + (NL / 8);
    for (int q = q0 + tid; q < q1; q += NTHR) {
        const int4   f = ((const int4*)fidx)[q];
        const int4   t = ((const int4*)tidx)[q];
        const float4 r = ((const float4*)xr)[q];
        float4 o;
        o.x = (ang[f.x] - ang[t.x]) * fast_rcp(r.x);
        o.y = (ang[f.y] - ang[t.y]) * fast_rcp(r.y);
        o.z = (ang[f.z] - ang[t.z]) * fast_rcp(r.z);
        o.w = (ang[f.w] - ang[t.w]) * fast_rcp(r.w);
        ((float4*)frow)[q] = o;                        // plain stores (nt hurt)
    }
}

extern "C" void kernel_launch(void* const* d_in, const int* in_sizes, int n_in,
                              void* d_out, int out_size, void* d_ws, size_t ws_size,
                              hipStream_t stream)
{
    const float* x   = (const float*)d_in[0];
    const int*   fi  = (const int*)  d_in[1];
    const int*   ti  = (const int*)  d_in[2];
    const float* xr  = (const float*)d_in[3];
    const float* lim = (const float*)d_in[4];

    float* out    = (float*)d_out;                      // (128, 41000)
    float* flows2 = out + (size_t)BATCH * ROW;          // (128, 320000)

    // ws: H u16 (10.24 MB) | cnt int (80 KB) | bins u32 (6.4 MB)
    ushort*   H    = (ushort*)d_ws;
    int*      cnt  = (int*)((char*)d_ws + (size_t)NBLK * NB * 2);
    unsigned* bins = (unsigned*)((char*)cnt + (size_t)NB * 4);

    void* args[] = { (void*)&x, (void*)&fi, (void*)&ti, (void*)&xr,
                     (void*)&lim, (void*)&H, (void*)&cnt, (void*)&bins,
                     (void*)&out, (void*)&flows2 };
    hipLaunchCooperativeKernel((const void*)mega_k, dim3(NBLK), dim3(NTHR),
                               args, SMEMB, stream);
}

// Round 12
// 113.711 us; speedup vs baseline: 5.8109x; 5.8109x over previous
//
#include <hip/hip_runtime.h>

#define NB     20000
#define NL     320000
#define NOTH   1000
#define BATCH  128
#define ROW    (2*NB + NOTH)   // 41000
#define CAP    80              // events/bus capacity; degree ~ Poisson(32), max ~60
#define NBLK   256             // histo/place blocks
#define LSEG   (NL/NBLK)       // 1250 lines per block
#define BCHUNK 8               // bus chunks (delta) — R8-identical
#define CB     (NB/BCHUNK)     // 2500 buses per block
#define NSLICE 2               // line slices (flows) — R8-identical
#define LPS    (NL/NSLICE)     // 160000 lines per slice

__device__ __forceinline__ float fast_rcp(float a)
{
    float r;
    asm volatile("v_rcp_f32 %0, %1" : "=v"(r) : "v"(a));
    return r;
}

// ============================ build: histo -> scan -> place =================
// histo_k: per-block LDS histogram of a 1250-line segment -> u8 partials
// (counts <= ~15 per block-segment; u8 halves H traffic vs u16).
__global__ __launch_bounds__(512) void histo_k(
    const int* __restrict__ fidx, const int* __restrict__ tidx,
    uchar* __restrict__ H)
{
    extern __shared__ uint h[];                       // NB uints = 80 KB
    for (int i = threadIdx.x; i < NB; i += 512) h[i] = 0u;
    __syncthreads();

    const int l0 = blockIdx.x * LSEG;
    for (int l = l0 + (int)threadIdx.x; l < l0 + LSEG; l += 512) {
        atomicAdd(&h[fidx[l]], 1u);                   // LDS atomics, CU-local
        atomicAdd(&h[tidx[l]], 1u);
    }
    __syncthreads();

    uint* __restrict__ Hrow = (uint*)(H + (size_t)blockIdx.x * NB);
    for (int i = threadIdx.x; i < NB / 4; i += 512) {
        const uint c0 = min(h[4 * i + 0], 255u), c1 = min(h[4 * i + 1], 255u);
        const uint c2 = min(h[4 * i + 2], 255u), c3 = min(h[4 * i + 3], 255u);
        Hrow[i] = c0 | (c1 << 8) | (c2 << 16) | (c3 << 24);
    }
}

// scan_k: per-bus exclusive prefix over the 256 u8 partials, IN PLACE.
// Wave-coalesced: lanes u..u+63 read/write contiguous bytes at each b.
// Totals <= ~60 so u8 prefix never overflows.
__global__ __launch_bounds__(512) void scan_k(
    uchar* __restrict__ H, int* __restrict__ cnt)
{
    const int u = blockIdx.x * 512 + (int)threadIdx.x;
    if (u >= NB) return;
    uint run = 0;
    for (int b = 0; b < NBLK; ++b) {
        const uint v = H[(size_t)b * NB + u];
        H[(size_t)b * NB + u] = (uchar)run;           // exclusive prefix
        run += v;
    }
    cnt[u] = (int)run;
}

// place_k: slot = global prefix (staged 20-KB u8 row in LDS) + local LDS rank.
// Event word: bits31:17 = other endpoint, bit16 = side, bits15:0 = bf16(rl).
__global__ __launch_bounds__(512) void place_k(
    const int* __restrict__ fidx, const int* __restrict__ tidx,
    const float* __restrict__ xr, const float* __restrict__ lim,
    const uchar* __restrict__ H, unsigned* __restrict__ bins)
{
    extern __shared__ char sm[];
    uint*  __restrict__ h    = (uint*)sm;             // NB uints = 80 KB
    uchar* __restrict__ pref = (uchar*)(sm + NB * 4); // NB u8    = 20 KB

    const uchar* __restrict__ Hrow = H + (size_t)blockIdx.x * NB;
    for (int i = threadIdx.x; i < NB; i += 512) h[i] = 0u;
    for (int i = threadIdx.x; i < NB / 16; i += 512)
        ((uint4*)pref)[i] = ((const uint4*)Hrow)[i];
    __syncthreads();

    const int l0 = blockIdx.x * LSEG;
    for (int l = l0 + (int)threadIdx.x; l < l0 + LSEG; l += 512) {
        const int fi = fidx[l];
        const int ti = tidx[l];
        union { float f; unsigned u; } c; c.f = xr[l] * lim[l];
        const unsigned rl16 = (c.u + 0x8000u) >> 16;

        const uint s0 = (uint)pref[fi] + atomicAdd(&h[fi], 1u);
        if (s0 < CAP) bins[(size_t)s0 * NB + fi] = ((unsigned)ti << 17) | rl16;
        const uint s1 = (uint)pref[ti] + atomicAdd(&h[ti], 1u);
        if (s1 < CAP) bins[(size_t)s1 * NB + ti] =
            ((unsigned)fi << 17) | (1u << 16) | rl16;
    }
}

// ============================ delta + copy (R8-identical) ===================
__global__ __launch_bounds__(1024) void delta_copy_k(
    const float* __restrict__ x, const int* __restrict__ cnt,
    const unsigned* __restrict__ bins, float* __restrict__ out)
{
    extern __shared__ float a[];                      // NB f32 = 80 KB
    const int b  = blockIdx.x % BATCH;                // XCD = b%8
    const int cb = blockIdx.x / BATCH;

    const float* __restrict__ xrow = x   + (size_t)b * ROW;
    float*       __restrict__ orow = out + (size_t)b * ROW;

    for (int i = threadIdx.x; i < NB / 4; i += 1024)
        ((float4*)a)[i] = ((const float4*)(xrow + NB))[i];
    __syncthreads();

    for (int i = threadIdx.x; i < CB / 4; i += 1024)
        ((float4*)(orow + cb * CB))[i] = ((const float4*)(xrow + cb * CB))[i];
    if (cb == 0)
        for (int i = threadIdx.x; i < NOTH / 4; i += 1024)
            ((float4*)(orow + 2 * NB))[i] = ((const float4*)(xrow + 2 * NB))[i];

    const int base = cb * CB;
    for (int bus = base + (int)threadIdx.x; bus < base + CB; bus += 1024) {
        const int   n  = min(cnt[bus], CAP);
        const float ab = a[bus];
        float ds = 0.0f;
        int k = 0;
        #define CONTRIB(W)                                                   \
        {                                                                    \
            const unsigned w  = (W);                                         \
            const int   other = (int)(w >> 17);                              \
            const float rl    = __uint_as_float((w & 0xFFFFu) << 16);        \
            const float ad    = ab - a[other];                               \
            if (fabsf(ad) > rl) {                                            \
                float hh = 0.5f * (copysignf(rl, ad) - ad);                  \
                if (w & (1u << 16)) hh = -hh;                                \
                ds += hh;                                                    \
            }                                                                \
        }
        for (; k + 4 <= n; k += 4) {
            const unsigned w0 = bins[(size_t)(k + 0) * NB + bus];
            const unsigned w1 = bins[(size_t)(k + 1) * NB + bus];
            const unsigned w2 = bins[(size_t)(k + 2) * NB + bus];
            const unsigned w3 = bins[(size_t)(k + 3) * NB + bus];
            CONTRIB(w0) CONTRIB(w1) CONTRIB(w2) CONTRIB(w3)
        }
        for (; k < n; ++k) CONTRIB(bins[(size_t)k * NB + bus])
        #undef CONTRIB
        orow[NB + bus] = ab + ds;
    }
}

// ============================ flows (R8-identical) ==========================
__global__ __launch_bounds__(1024) void flows_lds_k(
    const float* __restrict__ out, const int* __restrict__ fidx,
    const int* __restrict__ tidx, const float* __restrict__ xr,
    float* __restrict__ f2)
{
    extern __shared__ float a2[];                     // NB f32 = 80 KB
    const int b = blockIdx.x % BATCH;
    const int s = blockIdx.x / BATCH;

    const float* __restrict__ src = out + (size_t)b * ROW + NB;
    for (int i = threadIdx.x; i < NB / 4; i += 1024)
        ((float4*)a2)[i] = ((const float4*)src)[i];
    __syncthreads();

    float* __restrict__ frow = f2 + (size_t)b * NL;
    const int q0 = s * (LPS / 4);
    const int q1 = q0 + (LPS / 4);
    for (int q = q0 + (int)threadIdx.x; q < q1; q += 1024) {
        const int4   f = ((const int4*)fidx)[q];
        const int4   t = ((const int4*)tidx)[q];
        const float4 r = ((const float4*)xr)[q];
        float4 o;
        o.x = (a2[f.x] - a2[t.x]) * fast_rcp(r.x);
        o.y = (a2[f.y] - a2[t.y]) * fast_rcp(r.y);
        o.z = (a2[f.z] - a2[t.z]) * fast_rcp(r.z);
        o.w = (a2[f.w] - a2[t.w]) * fast_rcp(r.w);
        ((float4*)frow)[q] = o;
    }
}

extern "C" void kernel_launch(void* const* d_in, const int* in_sizes, int n_in,
                              void* d_out, int out_size, void* d_ws, size_t ws_size,
                              hipStream_t stream)
{
    const float* x   = (const float*)d_in[0];
    const int*   fi  = (const int*)  d_in[1];
    const int*   ti  = (const int*)  d_in[2];
    const float* xr  = (const float*)d_in[3];
    const float* lim = (const float*)d_in[4];

    float* out    = (float*)d_out;                      // (128, 41000)
    float* flows2 = out + (size_t)BATCH * ROW;          // (128, 320000)

    // ws layout: H u8 (5.12 MB) | cnt int (80 KB) | bins u32 (6.4 MB)
    uchar*    H    = (uchar*)d_ws;
    int*      cnt  = (int*)((char*)d_ws + (size_t)NBLK * NB);
    unsigned* bins = (unsigned*)((char*)cnt + (size_t)NB * 4);

    histo_k<<<dim3(NBLK), dim3(512), NB * sizeof(uint), stream>>>(fi, ti, H);

    scan_k<<<dim3((NB + 511) / 512), dim3(512), 0, stream>>>(H, cnt);

    place_k<<<dim3(NBLK), dim3(512), NB * 4 + NB, stream>>>(
        fi, ti, xr, lim, H, bins);

    delta_copy_k<<<dim3(BCHUNK * BATCH), dim3(1024), NB * sizeof(float), stream>>>(
        x, cnt, bins, out);

    flows_lds_k<<<dim3(NSLICE * BATCH), dim3(1024), NB * sizeof(float), stream>>>(
        out, fi, ti, xr, flows2);
}

// Round 13
// 110.120 us; speedup vs baseline: 6.0004x; 1.0326x over previous
//
#include <hip/hip_runtime.h>

#define NB     20000
#define NL     320000
#define NOTH   1000
#define BATCH  128
#define ROW    (2*NB + NOTH)   // 41000
#define CAP    80              // events/bus capacity; degree ~ Poisson(32), max ~60
#define NBLK   256             // histo/place blocks
#define LSEG   (NL/NBLK)       // 1250 lines per block
#define BCHUNK 8               // bus chunks (delta)
#define CB     (NB/BCHUNK)     // 2500 buses per block
#define NSLICE 2               // line slices (flows)
#define LPS    (NL/NSLICE)     // 160000 lines per slice

__device__ __forceinline__ float fast_rcp(float a)
{
    float r;
    asm volatile("v_rcp_f32 %0, %1" : "=v"(r) : "v"(a));
    return r;
}

// ============================ build: histo -> scan -> place =================
// histo_k: per-block LDS histogram of a 1250-line segment -> u8 partials.
// 1024 threads (2 blocks/CU at 80 KB): more waves hiding the atomic phase.
__global__ __launch_bounds__(1024) void histo_k(
    const int* __restrict__ fidx, const int* __restrict__ tidx,
    uchar* __restrict__ H)
{
    extern __shared__ uint h[];                       // NB uints = 80 KB
    for (int i = threadIdx.x; i < NB; i += 1024) h[i] = 0u;
    __syncthreads();

    const int l0 = blockIdx.x * LSEG;
    for (int l = l0 + (int)threadIdx.x; l < l0 + LSEG; l += 1024) {
        atomicAdd(&h[fidx[l]], 1u);                   // LDS atomics, CU-local
        atomicAdd(&h[tidx[l]], 1u);
    }
    __syncthreads();

    uint* __restrict__ Hrow = (uint*)(H + (size_t)blockIdx.x * NB);
    for (int i = threadIdx.x; i < NB / 4; i += 1024) {
        const uint c0 = min(h[4 * i + 0], 255u), c1 = min(h[4 * i + 1], 255u);
        const uint c2 = min(h[4 * i + 2], 255u), c3 = min(h[4 * i + 3], 255u);
        Hrow[i] = c0 | (c1 << 8) | (c2 << 16) | (c3 << 24);
    }
}

// scan_k: per-bus exclusive prefix over the 256 u8 partials, IN PLACE.
__global__ __launch_bounds__(512) void scan_k(
    uchar* __restrict__ H, int* __restrict__ cnt)
{
    const int u = blockIdx.x * 512 + (int)threadIdx.x;
    if (u >= NB) return;
    uint run = 0;
    for (int b = 0; b < NBLK; ++b) {
        const uint v = H[(size_t)b * NB + u];
        H[(size_t)b * NB + u] = (uchar)run;           // exclusive prefix
        run += v;
    }
    cnt[u] = (int)run;
}

// place_k: slot = global prefix (u8, staged) + local rank. Rank counters
// packed 2×u16 per u32 (counts <= ~60, no carry-out) -> LDS 60 KB ->
// 2 blocks/CU at 1024 threads: 4x the TLP hiding the scattered bin stores.
__global__ __launch_bounds__(1024) void place_k(
    const int* __restrict__ fidx, const int* __restrict__ tidx,
    const float* __restrict__ xr, const float* __restrict__ lim,
    const uchar* __restrict__ H, unsigned* __restrict__ bins)
{
    extern __shared__ char sm[];
    uint*  __restrict__ h    = (uint*)sm;             // NB/2 u32 = 40 KB
    uchar* __restrict__ pref = (uchar*)(sm + NB * 2); // NB u8    = 20 KB

    const uchar* __restrict__ Hrow = H + (size_t)blockIdx.x * NB;
    for (int i = threadIdx.x; i < NB / 2; i += 1024) h[i] = 0u;
    for (int i = threadIdx.x; i < NB / 16; i += 1024)
        ((uint4*)pref)[i] = ((const uint4*)Hrow)[i];
    __syncthreads();

    const int l0 = blockIdx.x * LSEG;
    for (int l = l0 + (int)threadIdx.x; l < l0 + LSEG; l += 1024) {
        const int fi = fidx[l];
        const int ti = tidx[l];
        union { float f; unsigned u; } c; c.f = xr[l] * lim[l];
        const unsigned rl16 = (c.u + 0x8000u) >> 16;

        const uint sh0  = 16u * (fi & 1);
        const uint r0   = (atomicAdd(&h[fi >> 1], 1u << sh0) >> sh0) & 0xFFFFu;
        const uint s0   = (uint)pref[fi] + r0;
        if (s0 < CAP) bins[(size_t)s0 * NB + fi] = ((unsigned)ti << 17) | rl16;

        const uint sh1  = 16u * (ti & 1);
        const uint r1   = (atomicAdd(&h[ti >> 1], 1u << sh1) >> sh1) & 0xFFFFu;
        const uint s1   = (uint)pref[ti] + r1;
        if (s1 < CAP) bins[(size_t)s1 * NB + ti] =
            ((unsigned)fi << 17) | (1u << 16) | rl16;
    }
}

// ============================ delta + copy (8-deep bin batch) ===============
__global__ __launch_bounds__(1024) void delta_copy_k(
    const float* __restrict__ x, const int* __restrict__ cnt,
    const unsigned* __restrict__ bins, float* __restrict__ out)
{
    extern __shared__ float a[];                      // NB f32 = 80 KB
    const int b  = blockIdx.x % BATCH;                // XCD = b%8
    const int cb = blockIdx.x / BATCH;

    const float* __restrict__ xrow = x   + (size_t)b * ROW;
    float*       __restrict__ orow = out + (size_t)b * ROW;

    for (int i = threadIdx.x; i < NB / 4; i += 1024)
        ((float4*)a)[i] = ((const float4*)(xrow + NB))[i];
    __syncthreads();

    for (int i = threadIdx.x; i < CB / 4; i += 1024)
        ((float4*)(orow + cb * CB))[i] = ((const float4*)(xrow + cb * CB))[i];
    if (cb == 0)
        for (int i = threadIdx.x; i < NOTH / 4; i += 1024)
            ((float4*)(orow + 2 * NB))[i] = ((const float4*)(xrow + 2 * NB))[i];

    const int base = cb * CB;
    for (int bus = base + (int)threadIdx.x; bus < base + CB; bus += 1024) {
        const int   n  = min(cnt[bus], CAP);
        const float ab = a[bus];
        float ds = 0.0f;
        int k = 0;
        #define CONTRIB(W)                                                   \
        {                                                                    \
            const unsigned w  = (W);                                         \
            const int   other = (int)(w >> 17);                              \
            const float rl    = __uint_as_float((w & 0xFFFFu) << 16);        \
            const float ad    = ab - a[other];                               \
            if (fabsf(ad) > rl) {                                            \
                float hh = 0.5f * (copysignf(rl, ad) - ad);                  \
                if (w & (1u << 16)) hh = -hh;                                \
                ds += hh;                                                    \
            }                                                                \
        }
        for (; k + 8 <= n; k += 8) {                  // 8 outstanding loads
            const unsigned w0 = bins[(size_t)(k + 0) * NB + bus];
            const unsigned w1 = bins[(size_t)(k + 1) * NB + bus];
            const unsigned w2 = bins[(size_t)(k + 2) * NB + bus];
            const unsigned w3 = bins[(size_t)(k + 3) * NB + bus];
            const unsigned w4 = bins[(size_t)(k + 4) * NB + bus];
            const unsigned w5 = bins[(size_t)(k + 5) * NB + bus];
            const unsigned w6 = bins[(size_t)(k + 6) * NB + bus];
            const unsigned w7 = bins[(size_t)(k + 7) * NB + bus];
            CONTRIB(w0) CONTRIB(w1) CONTRIB(w2) CONTRIB(w3)
            CONTRIB(w4) CONTRIB(w5) CONTRIB(w6) CONTRIB(w7)
        }
        for (; k + 4 <= n; k += 4) {
            const unsigned w0 = bins[(size_t)(k + 0) * NB + bus];
            const unsigned w1 = bins[(size_t)(k + 1) * NB + bus];
            const unsigned w2 = bins[(size_t)(k + 2) * NB + bus];
            const unsigned w3 = bins[(size_t)(k + 3) * NB + bus];
            CONTRIB(w0) CONTRIB(w1) CONTRIB(w2) CONTRIB(w3)
        }
        for (; k < n; ++k) CONTRIB(bins[(size_t)k * NB + bus])
        #undef CONTRIB
        orow[NB + bus] = ab + ds;
    }
}

// ============================ flows (R8/R12-identical) ======================
__global__ __launch_bounds__(1024) void flows_lds_k(
    const float* __restrict__ out, const int* __restrict__ fidx,
    const int* __restrict__ tidx, const float* __restrict__ xr,
    float* __restrict__ f2)
{
    extern __shared__ float a2[];                     // NB f32 = 80 KB
    const int b = blockIdx.x % BATCH;
    const int s = blockIdx.x / BATCH;

    const float* __restrict__ src = out + (size_t)b * ROW + NB;
    for (int i = threadIdx.x; i < NB / 4; i += 1024)
        ((float4*)a2)[i] = ((const float4*)src)[i];
    __syncthreads();

    float* __restrict__ frow = f2 + (size_t)b * NL;
    const int q0 = s * (LPS / 4);
    const int q1 = q0 + (LPS / 4);
    for (int q = q0 + (int)threadIdx.x; q < q1; q += 1024) {
        const int4   f = ((const int4*)fidx)[q];
        const int4   t = ((const int4*)tidx)[q];
        const float4 r = ((const float4*)xr)[q];
        float4 o;
        o.x = (a2[f.x] - a2[t.x]) * fast_rcp(r.x);
        o.y = (a2[f.y] - a2[t.y]) * fast_rcp(r.y);
        o.z = (a2[f.z] - a2[t.z]) * fast_rcp(r.z);
        o.w = (a2[f.w] - a2[t.w]) * fast_rcp(r.w);
        ((float4*)frow)[q] = o;
    }
}

extern "C" void kernel_launch(void* const* d_in, const int* in_sizes, int n_in,
                              void* d_out, int out_size, void* d_ws, size_t ws_size,
                              hipStream_t stream)
{
    const float* x   = (const float*)d_in[0];
    const int*   fi  = (const int*)  d_in[1];
    const int*   ti  = (const int*)  d_in[2];
    const float* xr  = (const float*)d_in[3];
    const float* lim = (const float*)d_in[4];

    float* out    = (float*)d_out;                      // (128, 41000)
    float* flows2 = out + (size_t)BATCH * ROW;          // (128, 320000)

    // ws layout: H u8 (5.12 MB) | cnt int (80 KB) | bins u32 (6.4 MB)
    uchar*    H    = (uchar*)d_ws;
    int*      cnt  = (int*)((char*)d_ws + (size_t)NBLK * NB);
    unsigned* bins = (unsigned*)((char*)cnt + (size_t)NB * 4);

    histo_k<<<dim3(NBLK), dim3(1024), NB * sizeof(uint), stream>>>(fi, ti, H);

    scan_k<<<dim3((NB + 511) / 512), dim3(512), 0, stream>>>(H, cnt);

    place_k<<<dim3(NBLK), dim3(1024), NB * 2 + NB, stream>>>(
        fi, ti, xr, lim, H, bins);

    delta_copy_k<<<dim3(BCHUNK * BATCH), dim3(1024), NB * sizeof(float), stream>>>(
        x, cnt, bins, out);

    flows_lds_k<<<dim3(NSLICE * BATCH), dim3(1024), NB * sizeof(float), stream>>>(
        out, fi, ti, xr, flows2);
}